// Round 6
// baseline (397.094 us; speedup 1.0000x reference)
//
#include <hip/hip_runtime.h>

// HomologicalConnectivityLoss: adj (8192x8192 fp32, bit-exact symmetric).
// loss = (n_comp-1)^2 + max(0, n_edges - N + n_comp)^2
//
// Ladder:
//  R1 767us: fused global union-find (pointer-chase poison).
//  R2 1553us: per-edge global atomicAdd append + global union-find.
//  R3 437us: LDS edge staging + single-block LDS union-find.
//  R4 415us: SV min-label propagation in LDS; scan 4-loads-in-flight.
//  R5 404us: scan 9-deep MLP; label streaming 8-deep prefetch.
//            Model: timed region = 2x1GiB harness poison fills (~321us @84%
//            HBM peak, uncontrollable) + ~70-83us ours.
//  R6 472us / R7 431us REGRESSIONS: edges-in-registers (VGPR cliff / still
//            worse at matched occupancy -> stream from L2).
//  R8 391us: star-grouped relax (per-row-run prefix-min, ~1.05 LDS
//            reads/edge) + row-run-ordered ebuf. Prediction matched.
//  R9 (this): NO-INIT restructure.
//    - scan block b writes edges to its OWN slice (b*2048: row-a run at +0,
//      row-b run at +1024) and stores raw counts gcnt[2b],[2b+1] and
//      gdiag[b] unconditionally -> no zeroed counters needed -> init
//      dispatch deleted (2 launches total), no global atomic in scan.
//    - label: runs are slice-aligned with ANALYTIC r (run1 r=b, run2
//      r=8191-b): star relax per run with constant r, no head-load.
//    - convergence flag via one __any ballot per wave (not per-edge LDS
//      store).
//    Caps: 1024 edges/row vs actual max ~50 (Poisson lam~19, sd~4.4);
//    clamp would deterministically fail the absmax check on this fixed
//    input (observable, not silent); n_edges stays exact via raw counts.
//
// Workspace map (ints): [0..8192) gcnt (na,nb per block),
// [8192..12288) gdiag, [12288..) slices: 4096 x 2048 u32.
// Needs ~34 MB; harness ws is 1 GiB (fills show 2x1GiB poison).

#define NN 8192
#define ROW_CAP 1024
#define SLICE 2048
#define LBL_THREADS 1024

// Block b processes rows b and NN-1-b (cols 0..r): balanced triangle scan.
// The two rows form one virtual float4 index space of 2049-2050 entries ->
// exactly 9 per thread at 256 threads. All 9 loads issued back-to-back
// (independent, predicated) before any processing: 9-deep MLP per thread.
__global__ __launch_bounds__(256) void scan_kernel(const float* __restrict__ adj,
                                                   int* __restrict__ gcnt,
                                                   int* __restrict__ gdiag,
                                                   unsigned int* __restrict__ slices) {
    __shared__ int na, nb;
    __shared__ unsigned int ea[ROW_CAP];
    __shared__ unsigned int eb[ROW_CAP];
    __shared__ int wsum4[4];
    if (threadIdx.x == 0) { na = 0; nb = 0; }
    __syncthreads();

    int b = blockIdx.x;
    int ra = b;
    int rb = NN - 1 - b;
    int nfa = (ra + 4) >> 2;          // ceil((ra+1)/4)
    int nfb = (rb + 4) >> 2;
    int tot = nfa + nfb;              // always 2049 or 2050 (<= 9*256)

    int t = threadIdx.x;
    int c1 = 0;                       // diagonal positives

    float4 v[9];
    int   rr[9];
    int   gg[9];
    bool  ok[9];

    // issue phase: 9 independent loads in flight
    #pragma unroll
    for (int k = 0; k < 9; ++k) {
        int vg = t + (k << 8);
        ok[k] = vg < tot;
        bool inA = vg < nfa;
        int r = inA ? ra : rb;
        int g = inA ? vg : vg - nfa;
        rr[k] = r;
        gg[k] = g;
        if (ok[k]) v[k] = ((const float4*)(adj + (size_t)r * NN))[g];
    }

    // process phase
    #pragma unroll
    for (int k = 0; k < 9; ++k) {
        if (!ok[k]) continue;
        int r  = rr[k];
        int j0 = gg[k] << 2;
        bool isA = (r == ra);
        float vv[4] = {v[k].x, v[k].y, v[k].z, v[k].w};
        #pragma unroll
        for (int c = 0; c < 4; ++c) {
            int j = j0 + c;
            bool pos = vv[c] > 0.0f;
            if (pos && j < r) {
                unsigned int e = ((unsigned)r << 13) | (unsigned)j;
                int kk = isA ? atomicAdd(&na, 1) : atomicAdd(&nb, 1);
                if (kk < ROW_CAP) { (isA ? ea : eb)[kk] = e; }
                // kk >= ROW_CAP impossible on this data (max ~50/row);
                // would deterministically fail absmax, not silently pass.
            }
            c1 += (pos && j == r) ? 1 : 0;
        }
    }

    // diag count: wave reduce -> LDS -> one store per block
    #pragma unroll
    for (int off = 32; off > 0; off >>= 1) c1 += __shfl_down(c1, off, 64);
    if ((t & 63) == 0) wsum4[t >> 6] = c1;

    __syncthreads();
    int na_c = na < ROW_CAP ? na : ROW_CAP;
    int nb_c = nb < ROW_CAP ? nb : ROW_CAP;
    if (t == 0) {
        gcnt[2 * b]     = na;   // raw: keeps n_edges exact even under clamp
        gcnt[2 * b + 1] = nb;
        gdiag[b] = wsum4[0] + wsum4[1] + wsum4[2] + wsum4[3];
    }
    unsigned int* sl = slices + (size_t)b * SLICE;
    for (int k = t; k < na_c; k += 256) sl[k] = ea[k];
    for (int k = t; k < nb_c; k += 256) sl[ROW_CAP + k] = eb[k];
}

// Single block: min-label propagation, labels in LDS, edges streamed from
// per-block slices (L2-warm after round 1). Thread t owns slices
// {t, t+1024, t+2048, t+3072}; each slice = two runs with ANALYTIC row:
// run1 r=b (at +0), run2 r=NN-1-b (at +1024). Star relax per run: lab[r]
// read once, running prefix-min mu (>= pairwise relax), deferred atomicMin
// on r, conditional atomicMin per j. Stale reads sound (labels only
// decrease; worst case an extra round). Convergence: if no atomicMin
// lowered anything and no shortcut moved, all edges have equal endpoint
// labels -> uniform label per component -> one self-labeled node each.
__global__ __launch_bounds__(LBL_THREADS) void label_final_kernel(
        const unsigned int* __restrict__ slices,
        const int* __restrict__ gcnt,
        const int* __restrict__ gdiag,
        float* __restrict__ out) {
    __shared__ int lab[NN];          // 32 KB
    __shared__ int changed;
    __shared__ int wsA[LBL_THREADS / 64];   // roots
    __shared__ int wsB[LBL_THREADS / 64];   // lower-edge total
    __shared__ int wsC[LBL_THREADS / 64];   // diag total
    int tid = threadIdx.x;
    for (int i = tid; i < NN; i += LBL_THREADS) lab[i] = i;

    // per-thread slice metadata (read once, kept in registers)
    int cnt_a[4], cnt_b[4];
    int my_edges = 0, my_diag = 0;
    #pragma unroll
    for (int s = 0; s < 4; ++s) {
        int b = tid + (s << 10);
        int a = gcnt[2 * b];
        int c = gcnt[2 * b + 1];
        my_edges += a + c;
        my_diag  += gdiag[b];
        cnt_a[s] = a < ROW_CAP ? a : ROW_CAP;
        cnt_b[s] = c < ROW_CAP ? c : ROW_CAP;
    }
    __syncthreads();

    for (;;) {
        if (tid == 0) changed = 0;
        __syncthreads();
        bool fired = false;

        // star relax over this thread's 8 runs (constant r per run)
        #pragma unroll
        for (int s = 0; s < 4; ++s) {
            int b = tid + (s << 10);
            const unsigned int* sl = slices + (size_t)b * SLICE;
            #pragma unroll
            for (int h = 0; h < 2; ++h) {
                int r = h ? (NN - 1 - b) : b;
                int n = h ? cnt_b[s] : cnt_a[s];
                const unsigned int* p = sl + (h ? ROW_CAP : 0);
                if (n <= 0) continue;
                int lr = lab[r];
                int mu = lr;
                int idx = 0;
                for (; idx + 4 <= n; idx += 4) {   // 4 edge loads in flight
                    unsigned int e0 = p[idx];
                    unsigned int e1 = p[idx + 1];
                    unsigned int e2 = p[idx + 2];
                    unsigned int e3 = p[idx + 3];
                    int j0 = (int)(e0 & (NN - 1)); int l0 = lab[j0];
                    int j1 = (int)(e1 & (NN - 1)); int l1 = lab[j1];
                    int j2 = (int)(e2 & (NN - 1)); int l2 = lab[j2];
                    int j3 = (int)(e3 & (NN - 1)); int l3 = lab[j3];
                    if (l0 < mu) mu = l0;
                    else if (mu < l0) { if (atomicMin(&lab[j0], mu) > mu) fired = true; }
                    if (l1 < mu) mu = l1;
                    else if (mu < l1) { if (atomicMin(&lab[j1], mu) > mu) fired = true; }
                    if (l2 < mu) mu = l2;
                    else if (mu < l2) { if (atomicMin(&lab[j2], mu) > mu) fired = true; }
                    if (l3 < mu) mu = l3;
                    else if (mu < l3) { if (atomicMin(&lab[j3], mu) > mu) fired = true; }
                }
                for (; idx < n; ++idx) {
                    unsigned int e = p[idx];
                    int j = (int)(e & (NN - 1));
                    int lj = lab[j];
                    if (lj < mu) mu = lj;
                    else if (mu < lj) { if (atomicMin(&lab[j], mu) > mu) fired = true; }
                }
                if (mu < lr) { if (atomicMin(&lab[r], mu) > mu) fired = true; }
            }
        }
        __syncthreads();

        // shortcut: two pointer-jumping passes (monotone, benign races;
        // disjoint i per thread so plain stores don't collide)
        #pragma unroll
        for (int sc = 0; sc < 2; ++sc) {
            for (int i = tid; i < NN; i += LBL_THREADS) {
                int l = lab[i];
                int ll = lab[l];
                if (ll < l) { lab[i] = ll; fired = true; }
            }
        }
        // one flag write per wave (uniform point, all lanes converged)
        if (__any(fired)) { if ((tid & 63) == 0) changed = 1; }
        __syncthreads();

        if (changed == 0) break;   // uniform decision (post-barrier read)
        __syncthreads();           // protect next round's reset vs this read
    }

    // reduce: roots (self-labeled), lower-edge total, diag total
    int cnt = 0;
    for (int i = tid; i < NN; i += LBL_THREADS) cnt += (lab[i] == i) ? 1 : 0;
    #pragma unroll
    for (int off = 32; off > 0; off >>= 1) {
        cnt      += __shfl_down(cnt, off, 64);
        my_edges += __shfl_down(my_edges, off, 64);
        my_diag  += __shfl_down(my_diag, off, 64);
    }
    if ((tid & 63) == 0) {
        wsA[tid >> 6] = cnt;
        wsB[tid >> 6] = my_edges;
        wsC[tid >> 6] = my_diag;
    }
    __syncthreads();
    if (tid == 0) {
        int roots = 0; long long lower = 0, diag = 0;
        #pragma unroll
        for (int w = 0; w < LBL_THREADS / 64; ++w) {
            roots += wsA[w]; lower += wsB[w]; diag += wsC[w];
        }
        long long total = 2LL * lower + diag;
        long long n_edges_i = total >> 1;               // exact integer // 2
        double n_comp = (double)roots;
        double comp_loss = (n_comp - 1.0) * (n_comp - 1.0);
        double betti = (double)n_edges_i - (double)NN + n_comp;
        double cyc = betti > 0.0 ? betti : 0.0;
        out[0] = (float)(comp_loss + cyc * cyc);
    }
}

extern "C" void kernel_launch(void* const* d_in, const int* in_sizes, int n_in,
                              void* d_out, int out_size, void* d_ws, size_t ws_size,
                              hipStream_t stream) {
    const float* adj = (const float*)d_in[0];
    int* ws = (int*)d_ws;
    int* gcnt  = ws;                                    // 8192 ints
    int* gdiag = ws + 8192;                             // 4096 ints
    unsigned int* slices = (unsigned int*)(ws + 12288); // 4096*2048 u32
    float* out = (float*)d_out;

    scan_kernel<<<NN / 2, 256, 0, stream>>>(adj, gcnt, gdiag, slices);
    label_final_kernel<<<1, LBL_THREADS, 0, stream>>>(slices, gcnt, gdiag, out);
}

// Round 7
// 390.543 us; speedup vs baseline: 1.0168x; 1.0168x over previous
//
#include <hip/hip_runtime.h>

// HomologicalConnectivityLoss: adj (8192x8192 fp32, bit-exact symmetric).
// loss = (n_comp-1)^2 + max(0, n_edges - N + n_comp)^2
//
// Ladder:
//  R1 767us: fused global union-find (pointer-chase poison).
//  R2 1553us: per-edge global atomicAdd append + global union-find.
//  R3 437us: LDS edge staging + single-block LDS union-find.
//  R4 415us: SV min-label propagation in LDS; scan 4-loads-in-flight.
//  R5 404us: scan 9-deep MLP; label streaming 8-deep prefetch.
//            Model: timed region = 2x1GiB harness poison fills (~321us @84%
//            HBM peak, uncontrollable) + ~70us ours.
//  R6 472us / R7 431us REGRESSIONS: edges-in-registers (VGPR cliff / still
//            worse at matched occupancy -> stream from L2).
//  R8 391us BEST: star-grouped relax (per-row-run prefix-min, ~1.05 LDS
//            reads/edge) + row-run-ordered compact ebuf. Prediction matched.
//  R9 397us NULL: no-init per-block-slice restructure — deleted init
//            dispatch but scattered writes/reads over 32MB cost more than
//            the launch saved. Pre-committed rule: structure overhead is
//            not a lever; revert.
//  R10 (this): exact revert to R8. Remaining headroom arithmetic:
//            scan 27us vs 21us HBM floor (134MB), label ~18us vs ~10us
//            LDS/round floor, launches ~6us => ~3% of wall. Fills (321us,
//            84% HBM peak) are harness-side and at their own roofline.
//
// Workspace (ints): ws[0]=lower-edge count, ws[1]=diag count,
// ws[2..] = edge buffer (u32 encoded (r<<13)|j, r>j).

#define NN 8192
#define ROW_LDS_CAP 1024    // expected ~19 edges/row; Poisson max ~50
#define LBL_THREADS 1024

__global__ __launch_bounds__(64) void init_kernel(int* counters) {
    if (threadIdx.x < 2) counters[threadIdx.x] = 0;
}

// Block b processes rows b and NN-1-b (cols 0..r): balanced triangle scan.
// The two rows form one virtual float4 index space of 2049-2050 entries ->
// exactly 9 per thread at 256 threads. All 9 loads issued back-to-back
// (independent, predicated) before any processing: 9-deep MLP per thread.
// Edges staged per-row in LDS; both rows flushed contiguously with ONE
// global atomicAdd per block -> ebuf is ordered in row-runs.
__global__ __launch_bounds__(256) void scan_kernel(const float* __restrict__ adj,
                                                   int* __restrict__ counters,
                                                   unsigned int* __restrict__ ebuf,
                                                   int cap) {
    __shared__ int na, nb;
    __shared__ int lds_base;
    __shared__ unsigned int ea[ROW_LDS_CAP];
    __shared__ unsigned int eb[ROW_LDS_CAP];
    if (threadIdx.x == 0) { na = 0; nb = 0; }
    __syncthreads();

    int b = blockIdx.x;
    int ra = b;
    int rb = NN - 1 - b;
    int nfa = (ra + 4) >> 2;          // ceil((ra+1)/4)
    int nfb = (rb + 4) >> 2;
    int tot = nfa + nfb;              // always 2049 or 2050 (<= 9*256)

    int t = threadIdx.x;
    int c1 = 0;                       // diagonal positives

    float4 v[9];
    int   rr[9];
    int   gg[9];
    bool  ok[9];

    // issue phase: 9 independent loads in flight
    #pragma unroll
    for (int k = 0; k < 9; ++k) {
        int vg = t + (k << 8);
        ok[k] = vg < tot;
        bool inA = vg < nfa;
        int r = inA ? ra : rb;
        int g = inA ? vg : vg - nfa;
        rr[k] = r;
        gg[k] = g;
        if (ok[k]) v[k] = ((const float4*)(adj + (size_t)r * NN))[g];
    }

    // process phase
    #pragma unroll
    for (int k = 0; k < 9; ++k) {
        if (!ok[k]) continue;
        int r  = rr[k];
        int j0 = gg[k] << 2;
        bool isA = (r == ra);
        float vv[4] = {v[k].x, v[k].y, v[k].z, v[k].w};
        #pragma unroll
        for (int c = 0; c < 4; ++c) {
            int j = j0 + c;
            bool pos = vv[c] > 0.0f;
            if (pos && j < r) {
                unsigned int e = ((unsigned)r << 13) | (unsigned)j;
                int kk = isA ? atomicAdd(&na, 1) : atomicAdd(&nb, 1);
                if (kk < ROW_LDS_CAP) { (isA ? ea : eb)[kk] = e; }
                else {  // never taken in practice; correctness fallback
                    int gk = atomicAdd(counters, 1);
                    if (gk < cap) ebuf[gk] = e;
                }
            }
            c1 += (pos && j == r) ? 1 : 0;
        }
    }

    // diag count: wave reduce, one atomic per wave
    #pragma unroll
    for (int off = 32; off > 0; off >>= 1) c1 += __shfl_down(c1, off, 64);
    if ((t & 63) == 0 && c1) atomicAdd(counters + 1, c1);

    __syncthreads();
    int na_c = na < ROW_LDS_CAP ? na : ROW_LDS_CAP;
    int nb_c = nb < ROW_LDS_CAP ? nb : ROW_LDS_CAP;
    if (t == 0) lds_base = atomicAdd(counters, na_c + nb_c);  // 1 per block
    __syncthreads();
    int base = lds_base;
    for (int k = t; k < na_c; k += 256) {
        int idx = base + k;
        if (idx < cap) ebuf[idx] = ea[k];
    }
    for (int k = t; k < nb_c; k += 256) {
        int idx = base + na_c + k;
        if (idx < cap) ebuf[idx] = eb[k];
    }
}

// Single block: min-label propagation, labels in LDS, edges streamed from
// L2 in per-thread CONSECUTIVE chunks (row-runs preserved by the scan).
// Star relax per run of equal r: lab[r] read once, running prefix-min mu
// (>= pairwise relax strength), deferred atomicMin on r at run end,
// conditional atomicMin per j. Stale reads are sound: labels only
// decrease; a stale (older, larger) value at worst triggers a harmless
// no-op atomic or an extra round. Fixpoint: no atomicMin lowers anything
// -> every edge has equal endpoint labels -> uniform label per component
// -> exactly one node per component keeps lab[i]==i.
__global__ __launch_bounds__(LBL_THREADS) void label_final_kernel(
        const unsigned int* __restrict__ ebuf,
        const int* __restrict__ counters,
        int cap, float* __restrict__ out) {
    __shared__ int lab[NN];          // 32 KB
    __shared__ int changed;
    __shared__ int wsum[LBL_THREADS / 64];
    int tid = threadIdx.x;
    for (int i = tid; i < NN; i += LBL_THREADS) lab[i] = i;

    int total_lower = counters[0];
    int m = total_lower < cap ? total_lower : cap;
    int cchunk = (m + LBL_THREADS - 1) / LBL_THREADS;   // ~76
    int s = tid * cchunk;
    int epos = s + cchunk; if (epos > m) epos = m;
    if (s > m) s = m;

    for (;;) {
        if (tid == 0) changed = 0;
        __syncthreads();

        // star-grouped relax over this thread's consecutive chunk
        {
            int cur_r = -1, lr = 0, mu = 0;
            auto proc = [&](unsigned int eg) {
                int r = (int)(eg >> 13);
                int j = (int)(eg & (NN - 1));
                int lj = lab[j];                  // independent, issues early
                if (r != cur_r) {
                    if (cur_r >= 0 && mu < lr) {
                        if (atomicMin(&lab[cur_r], mu) > mu) changed = 1;
                    }
                    cur_r = r; lr = lab[r]; mu = lr;
                }
                if (lj < mu) mu = lj;
                else if (mu < lj) {
                    if (atomicMin(&lab[j], mu) > mu) changed = 1;
                }
            };
            int idx = s;
            for (; idx + 4 <= epos; idx += 4) {   // 4 edge loads in flight
                unsigned int e0 = ebuf[idx];
                unsigned int e1 = ebuf[idx + 1];
                unsigned int e2 = ebuf[idx + 2];
                unsigned int e3 = ebuf[idx + 3];
                proc(e0); proc(e1); proc(e2); proc(e3);
            }
            for (; idx < epos; ++idx) proc(ebuf[idx]);
            if (cur_r >= 0 && mu < lr) {
                if (atomicMin(&lab[cur_r], mu) > mu) changed = 1;
            }
        }
        __syncthreads();

        // shortcut: two pointer-jumping passes (monotone, benign races;
        // each thread owns disjoint i, so stores don't collide)
        #pragma unroll
        for (int sc = 0; sc < 2; ++sc) {
            for (int i = tid; i < NN; i += LBL_THREADS) {
                int l = lab[i];
                int ll = lab[l];
                if (ll < l) { lab[i] = ll; changed = 1; }
            }
        }
        __syncthreads();

        if (changed == 0) break;   // uniform decision (post-barrier read)
        __syncthreads();           // protect next round's reset vs this read
    }

    // count self-labeled nodes = component count
    int cnt = 0;
    for (int i = tid; i < NN; i += LBL_THREADS) cnt += (lab[i] == i) ? 1 : 0;
    #pragma unroll
    for (int off = 32; off > 0; off >>= 1) cnt += __shfl_down(cnt, off, 64);
    if ((tid & 63) == 0) wsum[tid >> 6] = cnt;
    __syncthreads();
    if (tid == 0) {
        int roots = 0;
        #pragma unroll
        for (int w = 0; w < LBL_THREADS / 64; ++w) roots += wsum[w];
        long long total = 2LL * (long long)total_lower + (long long)counters[1];
        long long n_edges_i = total >> 1;               // exact integer // 2
        double n_comp = (double)roots;
        double comp_loss = (n_comp - 1.0) * (n_comp - 1.0);
        double betti = (double)n_edges_i - (double)NN + n_comp;
        double cyc = betti > 0.0 ? betti : 0.0;
        out[0] = (float)(comp_loss + cyc * cyc);
    }
}

extern "C" void kernel_launch(void* const* d_in, const int* in_sizes, int n_in,
                              void* d_out, int out_size, void* d_ws, size_t ws_size,
                              hipStream_t stream) {
    const float* adj = (const float*)d_in[0];
    int* ws = (int*)d_ws;
    int* counters = ws;                       // [0]=lower edges, [1]=diag
    unsigned int* ebuf = (unsigned int*)(ws + 2);
    long long cap_ll = (long long)(ws_size / 4) - 2;
    int cap = cap_ll > 0x7fffffff ? 0x7fffffff : (cap_ll < 0 ? 0 : (int)cap_ll);
    float* out = (float*)d_out;

    init_kernel<<<1, 64, 0, stream>>>(counters);
    scan_kernel<<<NN / 2, 256, 0, stream>>>(adj, counters, ebuf, cap);
    label_final_kernel<<<1, LBL_THREADS, 0, stream>>>(ebuf, counters, cap, out);
}